// Round 8
// baseline (149.467 us; speedup 1.0000x reference)
//
#include <hip/hip_runtime.h>

#define DIM     128
#define NCODES  1024
#define TILE_M  64
#define FLAGThr 0.018f       // acc-units: fp16 Hoeffding 0.010 + 2x pack err 0.008
#define RPB     8            // refine rows per block
#define RGRID   512          // refine grid

typedef __attribute__((ext_vector_type(8))) _Float16 half8;
typedef __attribute__((ext_vector_type(4))) _Float16 half4;
typedef __attribute__((ext_vector_type(4))) float    f32x4;

// ws layout:
//      0 : e2d    (1024 double)          8 KB
//   8192 : e2f    (1024 float)           4 KB
//  12288 : eh     (1024 codes x 256 B, granule-swizzled fp16)  256 KB
// 274432 : embedT (128*1024 float)     512 KB
// 798720 : cnt    (int)
// 798976 : list   (65536 int)          256 KB

// async 16B/lane global->LDS copy (DMA engine; wave-uniform base + lane*16)
typedef __attribute__((address_space(1))) const void gv_t;
typedef __attribute__((address_space(3))) void       lv_t;
__device__ __forceinline__ void dma16(const void* g, void* l) {
  __builtin_amdgcn_global_load_lds((gv_t*)g, (lv_t*)l, 16, 0, 0);
}

// -------- setup: e2 f32/f64, swizzled fp16 codebook image, embedT ----------
// eh image: code c occupies 256 B; 16B granule j (dims 8j..8j+7) stored at
// granule (j ^ (c & 15)) -> bank-conflict-free ds_read_b128 in pass1.
__global__ __launch_bounds__(256) void setup_kernel(
    const float* __restrict__ embed, double* __restrict__ e2d,
    float* __restrict__ e2f, unsigned char* __restrict__ eh,
    float* __restrict__ embedT, int* __restrict__ cnt)
{
  __shared__ float tile[64][132];
  __shared__ double psum[4][64];
  if (blockIdx.x == 0 && threadIdx.x == 0) *cnt = 0;
  const int c0 = blockIdx.x * 64;            // 16 blocks x 64 codes
  const int t  = threadIdx.x;

  const f32x4* E4 = (const f32x4*)(embed + (size_t)c0 * DIM);
  #pragma unroll
  for (int i = 0; i < 8; ++i) {
    int e = t + i * 256;                     // 2048 float4s = 64x128
    int r = e >> 5, c4 = e & 31;
    f32x4 v = E4[e];
    *(f32x4*)&tile[r][c4 * 4] = v;
    half4 h;
    h[0] = (_Float16)v[0]; h[1] = (_Float16)v[1];
    h[2] = (_Float16)v[2]; h[3] = (_Float16)v[3];
    int j = c4 >> 1;                         // granule, swizzled by code
    *(half4*)(eh + (size_t)(c0 + r) * 256 + ((j ^ (r & 15)) * 16) + (c4 & 1) * 8) = h;
  }
  __syncthreads();

  {
    int r = t & 63, part = t >> 6;
    double s = 0.0;
    #pragma unroll
    for (int k = 0; k < 32; ++k) {
      float v = tile[r][part * 32 + k];
      s += (double)v * v;
    }
    psum[part][r] = s;
  }
  __syncthreads();
  if (t < 64) {
    double s = psum[0][t] + psum[1][t] + psum[2][t] + psum[3][t];
    e2d[c0 + t] = s;
    e2f[c0 + t] = (float)s;
  }

  #pragma unroll
  for (int i = 0; i < 32; ++i) {
    int idx = t + i * 256;                   // 8192 = 128k x 64c
    int k = idx >> 6, c = idx & 63;
    embedT[(size_t)k * NCODES + c0 + c] = tile[c][k];
  }
}

// -------- pass1 v7: global_load_lds double-buffered B, 3 blocks/CU ---------
// acc = x.e - 0.5*e2 - 16 (init in MFMA C); argmax(acc) == argmin dist.
// Index in low 10 mantissa bits; rows with top-2 gap <= FLAGThr re-decided
// exactly by refine2. A-frags register-resident; B chunks (64 codes = 16 KB)
// DMA'd via global_load_lds into ping-pong LDS buffers; ONE barrier/chunk,
// DMA issued at iteration top so the barrier vmcnt(0) drain is ~free.
// LDS 51.5 KB -> 3 blocks/CU (12 waves/CU).
__global__ __launch_bounds__(256, 3) void pass1_kernel(
    const float* __restrict__ x, const float* __restrict__ embed,
    const unsigned char* __restrict__ eh, const float* __restrict__ e2f,
    float* __restrict__ outQ, float* __restrict__ outIdx,
    int* __restrict__ cnt, int* __restrict__ list)
{
  __shared__ __align__(16) unsigned char lds[49152];  // [0,16K) x  [16K,32K) buf0  [32K,48K) buf1
  __shared__ float rb_best[4][TILE_M];
  __shared__ float rb_sec [4][TILE_M];
  __shared__ int   fidx[TILE_M];

  const int tid  = threadIdx.x;
  const int row0 = blockIdx.x * TILE_M;
  const int l  = tid & 63, w = tid >> 6;
  const int rl = l & 15,  q = l >> 4;

  // issue chunk-0 DMA first (latency hides under x staging)
  {
    int off = (w * 4 + (tid & 63) / 64) * 0;  // (dummy to keep w live)
    (void)off;
    #pragma unroll
    for (int i = 0; i < 4; ++i) {
      int boff = (i * 4 + w) * 1024 + l * 16;
      dma16(eh + boff, lds + 16384 + boff);
    }
  }

  // stage x tile: 64 rows x 256 B fp16, granule-swizzled like eh
  {
    #pragma unroll
    for (int i = 0; i < 4; ++i) {
      int g = tid + i * 256;                 // 1024 granules
      int r = g >> 4, j = g & 15;
      const f32x4* xs = (const f32x4*)(x + (size_t)(row0 + r) * DIM + j * 8);
      f32x4 v0 = xs[0], v1 = xs[1];
      half8 h;
      h[0] = (_Float16)v0[0]; h[1] = (_Float16)v0[1];
      h[2] = (_Float16)v0[2]; h[3] = (_Float16)v0[3];
      h[4] = (_Float16)v1[0]; h[5] = (_Float16)v1[1];
      h[6] = (_Float16)v1[2]; h[7] = (_Float16)v1[3];
      *(half8*)(lds + r * 256 + (j ^ (r & 15)) * 16) = h;
    }
  }
  __syncthreads();

  // A fragments: 4 m-subs x 4 k-steps, register-resident for all 1024 codes
  half8 afrag[4][4];
  #pragma unroll
  for (int m = 0; m < 4; ++m)
    #pragma unroll
    for (int ks = 0; ks < 4; ++ks)
      afrag[m][ks] = *(const half8*)(lds + (m * 16 + rl) * 256 + ((ks * 4 + q) ^ rl) * 16);

  float bestp[16], secp[16];
  #pragma unroll
  for (int s = 0; s < 16; ++s) { bestp[s] = -3.0e38f; secp[s] = -3.3e38f; }

  float e2cur = e2f[w * 16 + rl];            // chunk-0 e2 prefetch

  #pragma unroll 2
  for (int ch = 0; ch < 16; ++ch) {
    unsigned char* bufC = lds + 16384 + (ch & 1) * 16384;
    // issue next-chunk DMA into the other buffer (drained at this barrier)
    if (ch < 15) {
      unsigned char* bufN = lds + 16384 + ((ch + 1) & 1) * 16384;
      const unsigned char* src = eh + (size_t)(ch + 1) * 16384;
      #pragma unroll
      for (int i = 0; i < 4; ++i) {
        int boff = (i * 4 + w) * 1024 + l * 16;
        dma16(src + boff, bufN + boff);
      }
    }
    float e2nxt = (ch < 15) ? e2f[(ch + 1) * 64 + w * 16 + rl] : 0.f;

    const int codeG = ch * 64 + w * 16 + rl; // wave-private 16-code slice
    const float vinit = fmaf(-0.5f, e2cur, -16.0f);

    half8 bfrag[4];
    #pragma unroll
    for (int ks = 0; ks < 4; ++ks)
      bfrag[ks] = *(const half8*)(bufC + (w * 16 + rl) * 256 + ((ks * 4 + q) ^ rl) * 16);

    f32x4 acc[4];
    #pragma unroll
    for (int m = 0; m < 4; ++m) acc[m] = (f32x4){vinit, vinit, vinit, vinit};
    #pragma unroll
    for (int ks = 0; ks < 4; ++ks)
      #pragma unroll
      for (int m = 0; m < 4; ++m)
        acc[m] = __builtin_amdgcn_mfma_f32_16x16x32_f16(afrag[m][ks], bfrag[ks], acc[m], 0, 0, 0);

    #pragma unroll
    for (int m = 0; m < 4; ++m)
      #pragma unroll
      for (int r = 0; r < 4; ++r) {
        const int s = m * 4 + r;
        float scp = __int_as_float((__float_as_int(acc[m][r]) & ~1023) | codeG);
        secp[s]  = __builtin_amdgcn_fmed3f(scp, bestp[s], secp[s]);
        bestp[s] = fmaxf(bestp[s], scp);
      }

    e2cur = e2nxt;
    __syncthreads();
  }

  // merge across the 16 lanes of each quarter (same rows, different codes)
  #pragma unroll
  for (int off = 1; off < 16; off <<= 1) {
    #pragma unroll
    for (int s = 0; s < 16; ++s) {
      float ob = __shfl_xor(bestp[s], off, 16);
      float os = __shfl_xor(secp[s],  off, 16);
      secp[s]  = fmaxf(__builtin_amdgcn_fmed3f(bestp[s], ob, secp[s]), os);
      bestp[s] = fmaxf(bestp[s], ob);
    }
  }
  if (rl == 0) {
    #pragma unroll
    for (int m = 0; m < 4; ++m)
      #pragma unroll
      for (int r = 0; r < 4; ++r) {
        int s = m * 4 + r;
        int row = m * 16 + q * 4 + r;
        rb_best[w][row] = bestp[s];
        rb_sec [w][row] = secp[s];
      }
  }
  __syncthreads();

  // merge the 4 waves (disjoint code sets), emit index + flag near-ties
  if (tid < TILE_M) {
    float bv = rb_best[0][tid], sv = rb_sec[0][tid];
    #pragma unroll
    for (int ww = 1; ww < 4; ++ww) {
      float ob = rb_best[ww][tid], os = rb_sec[ww][tid];
      sv = fmaxf(__builtin_amdgcn_fmed3f(bv, ob, sv), os);
      bv = fmaxf(bv, ob);
    }
    int bi = __float_as_int(bv) & 1023;
    int grow = row0 + tid;
    outIdx[grow] = (float)bi;
    fidx[tid] = bi;
    if (bv - sv <= FLAGThr) {
      int p = atomicAdd(cnt, 1);
      list[p] = grow;
    }
  }
  __syncthreads();

  // gather quantize = embed[idx] (coalesced writes, L2-hot embed reads)
  {
    const f32x4* E4   = (const f32x4*)embed;
    f32x4*       out4 = (f32x4*)(outQ + (size_t)row0 * DIM);
    #pragma unroll
    for (int i = 0; i < 8; ++i) {
      int e = tid + i * 256;
      int r = e >> 5, c4 = e & 31;
      out4[e] = E4[fidx[r] * 32 + c4];
    }
  }
}

// -------- refine v3: RPB=8 coalesced f32 rescan via embedT, f64 decision ---
__global__ __launch_bounds__(256) void refine2_kernel(
    const float* __restrict__ x, const float* __restrict__ embed,
    const float* __restrict__ embedT,
    const double* __restrict__ e2d, const float* __restrict__ e2f,
    float* __restrict__ outQ, float* __restrict__ outIdx,
    const int* __restrict__ cnt, const int* __restrict__ list)
{
  __shared__ float xsf[DIM * RPB];           // xsf[k*8 + r]
  __shared__ float rb1[RPB][4], rb2[RPB][4];
  __shared__ int   ri1[RPB][4], ri2[RPB][4];
  __shared__ int   cand[RPB][2];

  const int t = threadIdx.x;
  const int l = t & 63, w = t >> 6;
  const int n = *cnt;

  for (int base = blockIdx.x * RPB; base < n; base += RGRID * RPB) {
    const int nr = min(RPB, n - base);
    #pragma unroll
    for (int i = 0; i < 4; ++i) {
      int idx = t + i * 256;                 // 1024 = 8 rows x 128 dims
      int r = idx >> 7, k = idx & 127;
      float v = 0.f;
      if (r < nr) v = x[(size_t)list[base + r] * DIM + k];
      xsf[k * RPB + r] = v;
    }
    __syncthreads();

    // thread t owns codes 4t..4t+3; fully coalesced embedT stream
    f32x4 dot[RPB];
    #pragma unroll
    for (int r = 0; r < RPB; ++r) dot[r] = (f32x4){0.f, 0.f, 0.f, 0.f};
    const f32x4* eT4 = (const f32x4*)embedT;
    #pragma unroll 4
    for (int k = 0; k < DIM; ++k) {
      f32x4 e4 = eT4[k * 256 + t];
      f32x4 xa = *(const f32x4*)&xsf[k * RPB];
      f32x4 xb = *(const f32x4*)&xsf[k * RPB + 4];
      #pragma unroll
      for (int r = 0; r < 4; ++r) {
        dot[r][0] = fmaf(xa[r], e4[0], dot[r][0]);
        dot[r][1] = fmaf(xa[r], e4[1], dot[r][1]);
        dot[r][2] = fmaf(xa[r], e4[2], dot[r][2]);
        dot[r][3] = fmaf(xa[r], e4[3], dot[r][3]);
        dot[r+4][0] = fmaf(xb[r], e4[0], dot[r+4][0]);
        dot[r+4][1] = fmaf(xb[r], e4[1], dot[r+4][1]);
        dot[r+4][2] = fmaf(xb[r], e4[2], dot[r+4][2]);
        dot[r+4][3] = fmaf(xb[r], e4[3], dot[r+4][3]);
      }
    }

    // per-thread top-2 over 4 codes, then wave + block merges
    #pragma unroll
    for (int r = 0; r < RPB; ++r) {
      float b1 = 3.4e38f, b2 = 3.4e38f; int i1 = 0, i2 = 0;
      #pragma unroll
      for (int j = 0; j < 4; ++j) {
        int c = 4 * t + j;
        float sc = fmaf(-2.0f, dot[r][j], e2f[c]);
        bool better = (sc < b1);                 // ties keep lower index
        float lv = better ? b1 : sc;  int li = better ? i1 : c;
        if (better) { b1 = sc; i1 = c; }
        bool t2 = (lv < b2) || (lv == b2 && li < i2);
        if (t2) { b2 = lv; i2 = li; }
      }
      #pragma unroll
      for (int off = 1; off < 64; off <<= 1) {
        float o1 = __shfl_xor(b1, off, 64); int oi1 = __shfl_xor(i1, off, 64);
        float o2 = __shfl_xor(b2, off, 64); int oi2 = __shfl_xor(i2, off, 64);
        bool take = (o1 < b1) || (o1 == b1 && oi1 < i1);
        float n1 = take ? o1 : b1; int ni1 = take ? oi1 : i1;
        float lo = take ? b1 : o1; int loi = take ? i1 : oi1;
        float c2v = take ? o2 : b2; int c2i = take ? oi2 : i2;
        bool u2 = (c2v < lo) || (c2v == lo && c2i < loi);
        b1 = n1; i1 = ni1;
        b2 = u2 ? c2v : lo; i2 = u2 ? c2i : loi;
      }
      if (l == 0) { rb1[r][w] = b1; ri1[r][w] = i1; rb2[r][w] = b2; ri2[r][w] = i2; }
    }
    __syncthreads();

    if (t < RPB) {
      float v1 = rb1[t][0], v2 = rb2[t][0]; int j1 = ri1[t][0], j2 = ri2[t][0];
      #pragma unroll
      for (int ww = 1; ww < 4; ++ww) {
        float o1 = rb1[t][ww], o2 = rb2[t][ww]; int oi1 = ri1[t][ww], oi2 = ri2[t][ww];
        bool take = (o1 < v1) || (o1 == v1 && oi1 < j1);
        float n1 = take ? o1 : v1; int ni1 = take ? oi1 : j1;
        float lo = take ? v1 : o1; int loi = take ? j1 : oi1;
        float c2v = take ? o2 : v2; int c2i = take ? oi2 : j2;
        bool u2 = (c2v < lo) || (c2v == lo && c2i < loi);
        v1 = n1; j1 = ni1; v2 = u2 ? c2v : lo; j2 = u2 ? c2i : loi;
      }
      cand[t][0] = j1; cand[t][1] = j2;
    }
    __syncthreads();

    // f64 rescore: wave w handles rows w and w+4
    for (int rr = w; rr < nr; rr += 4) {
      int c1 = cand[rr][0], c2 = cand[rr][1];
      float xa = xsf[l * RPB + rr], xb = xsf[(l + 64) * RPB + rr];
      double p1 = (double)xa * (double)embed[(size_t)c1 * DIM + l]
                + (double)xb * (double)embed[(size_t)c1 * DIM + 64 + l];
      double p2 = (double)xa * (double)embed[(size_t)c2 * DIM + l]
                + (double)xb * (double)embed[(size_t)c2 * DIM + 64 + l];
      #pragma unroll
      for (int off = 1; off < 64; off <<= 1) {
        p1 += __shfl_xor(p1, off, 64);
        p2 += __shfl_xor(p2, off, 64);
      }
      double s1 = e2d[c1] - 2.0 * p1;
      double s2 = e2d[c2] - 2.0 * p2;
      int widx = ((s2 < s1) || (s2 == s1 && c2 < c1)) ? c2 : c1;
      int row = list[base + rr];
      if (l == 0) outIdx[row] = (float)widx;
      outQ[(size_t)row * DIM + l]      = embed[(size_t)widx * DIM + l];
      outQ[(size_t)row * DIM + 64 + l] = embed[(size_t)widx * DIM + 64 + l];
    }
    __syncthreads();   // xsf reused next trip
  }
}

extern "C" void kernel_launch(void* const* d_in, const int* in_sizes, int n_in,
                              void* d_out, int out_size, void* d_ws, size_t ws_size,
                              hipStream_t stream) {
  const float* x     = (const float*)d_in[0];
  const float* embed = (const float*)d_in[1];
  const int N = in_sizes[0] / DIM;             // 65536 rows

  float* out    = (float*)d_out;
  float* outQ   = out;                         // [N*128] quantize
  float* outIdx = out + (size_t)N * DIM;       // [N] indices as float

  char* ws = (char*)d_ws;
  double*        e2d  = (double*)       (ws);
  float*         e2f  = (float*)        (ws + 8192);
  unsigned char* eh   = (unsigned char*)(ws + 12288);
  float*         eT   = (float*)        (ws + 274432);
  int*           cnt  = (int*)          (ws + 798720);
  int*           list = (int*)          (ws + 798976);

  setup_kernel  <<<NCODES / 64, 256, 0, stream>>>(embed, e2d, e2f, eh, eT, cnt);
  pass1_kernel  <<<N / TILE_M,  256, 0, stream>>>(x, embed, eh, e2f, outQ, outIdx, cnt, list);
  refine2_kernel<<<RGRID,       256, 0, stream>>>(x, embed, eT, e2d, e2f, outQ, outIdx, cnt, list);
}